// Round 3
// baseline (1746.935 us; speedup 1.0000x reference)
//
#include <hip/hip_runtime.h>
#include <stdint.h>

#define NF 3000
#define NB 1500

// ---------------------------------------------------------------------------
// math helpers
// ---------------------------------------------------------------------------
__device__ __forceinline__ float signf(float v) {
    return (v > 0.f) ? 1.f : ((v < 0.f) ? -1.f : 0.f);
}

__device__ void ball_to_cube(float x, float y, float z, float b[3])
{
    const float EPS = 1e-8f;
    const float FOUR_OVER_PI = 1.2732395447351628f;  // float(4.0/pi)
    float sq    = x*x + y*y + z*z;
    float norm  = sqrtf(fmaxf(sq, EPS));
    float xy_sq = x*x + y*y;
    bool  polar = (1.25f*z*z > xy_sq);
    float s_p = sqrtf(3.0f*norm / (norm + fabsf(z) + EPS));
    float s_e = norm / sqrtf(fmaxf(xy_sq, EPS));
    float cx = polar ? x*s_p : x*s_e;
    float cy = polar ? y*s_p : y*s_e;
    float cz = polar ? signf(z)*norm : 1.5f*z;
    float nxy = sqrtf(fmaxf(cx*cx + cy*cy, EPS));
    bool  xdom = fabsf(cy) <= fabsf(cx);
    float sx = (fabsf(cx) > EPS) ? cx : 1.0f;
    float sy = (fabsf(cy) > EPS) ? cy : 1.0f;
    float bx1 = signf(cx)*nxy;
    float by1 = bx1*FOUR_OVER_PI*atanf(cy/sx);
    float by2 = signf(cy)*nxy;
    float bx2 = by2*FOUR_OVER_PI*atanf(cx/sy);
    float bx = xdom ? bx1 : bx2;
    float by = xdom ? by1 : by2;
    if (cx*cx + cy*cy < EPS) { bx = 0.f; by = 0.f; }
    if (sq < EPS)            { bx = 0.f; by = 0.f; cz = 0.f; }
    b[0] = bx; b[1] = by; b[2] = cz;
}

// ---------------------------------------------------------------------------
// integrate: v1 = v0 + DT*a ; p1 = p0 + DT*(v0+v1)*0.5 ; fluid_feats rows
// ---------------------------------------------------------------------------
__global__ __launch_bounds__(256)
void integrate_kernel(const float* __restrict__ p0, const float* __restrict__ v0,
                      const float* __restrict__ a,  const float* __restrict__ other,
                      const float* __restrict__ v0enc,
                      float* __restrict__ p1, float* __restrict__ ff)
{
    int t = blockIdx.x*blockDim.x + threadIdx.x;
    if (t >= NF*3) return;
    float vv = v0[t];
    float v1 = vv + 0.1f*a[t];
    float u  = vv + v1;
    float u2 = 0.1f*u;
    float u3 = u2*0.5f;
    p1[t] = p0[t] + u3;
    int n = t/3, j = t - 3*n;
    ff[n*9 + 0 + j] = v1;        // s=0: v1
    ff[n*9 + 3 + j] = other[t];  // s=1: other_feats
    ff[n*9 + 6 + j] = v0enc[t];  // s=2: v0_enc
}

// ---------------------------------------------------------------------------
// exact top-64 (smallest d2, ties -> smaller index == jax.lax.top_k) ; output
// sorted ascending by (d2, idx) to match JAX summation order.
// block per query; 64-bit keys (d2_bits<<32)|idx ; 8-pass MSB radix select
// with parallel (Hillis-Steele) digit-histogram scan.
// ---------------------------------------------------------------------------
template<int LPT, bool SELFX, bool MASK>
__global__ __launch_bounds__(256)
void knn_kernel(const float* __restrict__ qpos, const float* __restrict__ cpos, int M,
                const float* __restrict__ mask,
                int* __restrict__ idxout, float* __restrict__ d2out)
{
    __shared__ unsigned hist[256];
    __shared__ unsigned long long s_prefix;
    __shared__ int s_rem;
    __shared__ int s_cnt;
    __shared__ uint64_t skeys[64];

    int n = blockIdx.x;
    int tid = threadIdx.x;
    float qx = qpos[n*3+0], qy = qpos[n*3+1], qz = qpos[n*3+2];

    uint64_t keys[LPT];
#pragma unroll
    for (int i = 0; i < LPT; ++i) {
        int c = i*256 + tid;
        uint64_t key = ~0ull;
        if (c < M) {
            float dx = __fadd_rn(qx, -cpos[c*3+0]);
            float dy = __fadd_rn(qy, -cpos[c*3+1]);
            float dz = __fadd_rn(qz, -cpos[c*3+2]);
            // non-contracted, left-to-right: (dx*dx + dy*dy) + dz*dz
            float d2 = __fadd_rn(__fadd_rn(__fmul_rn(dx,dx), __fmul_rn(dy,dy)),
                                 __fmul_rn(dz,dz));
            if (SELFX && c == n) d2 = 1e30f;
            if (MASK && !(mask[c] > 0.f)) d2 = 1e30f;
            key = ((uint64_t)__float_as_uint(d2) << 32) | (unsigned)c;
        }
        keys[i] = key;
    }

    uint64_t prefix = 0;
    int rem = 64;
    for (int pass = 0; pass < 8; ++pass) {
        int shift = 56 - 8*pass;
        hist[tid] = 0;
        __syncthreads();
#pragma unroll
        for (int i = 0; i < LPT; ++i) {
            uint64_t k = keys[i];
            // pass 0: (k>>56)>>8 == 0 == prefix  (well-defined, no branch)
            bool act = (((k >> shift) >> 8) == prefix);
            if (act) atomicAdd(&hist[(unsigned)((k >> shift) & 0xff)], 1u);
        }
        __syncthreads();
        // inclusive scan of hist[256] (in place, Hillis-Steele)
        unsigned own = hist[tid];
#pragma unroll
        for (int off = 1; off < 256; off <<= 1) {
            unsigned v = (tid >= off) ? hist[tid - off] : 0u;
            __syncthreads();
            hist[tid] += v;
            __syncthreads();
        }
        unsigned inc = hist[tid];
        unsigned exc = inc - own;
        // exactly one digit satisfies exc < rem <= inc (cum monotone, total>=rem)
        if (exc < (unsigned)rem && inc >= (unsigned)rem) {
            s_prefix = (prefix << 8) | (unsigned)tid;
            s_rem = rem - (int)exc;
        }
        __syncthreads();
        prefix = s_prefix;
        rem = s_rem;
        __syncthreads();
    }
    uint64_t kth = prefix;  // exact 64th-smallest key
    if (tid == 0) s_cnt = 0;
    __syncthreads();
#pragma unroll
    for (int i = 0; i < LPT; ++i) {
        uint64_t k = keys[i];
        if (k <= kth) {
            int p = atomicAdd(&s_cnt, 1);
            skeys[p] = k;
        }
    }
    __syncthreads();
    // rank-sort the 64 winners (keys unique -> ranks unique)
    if (tid < 64) {
        uint64_t key = skeys[tid];
        int rank = 0;
        for (int j = 0; j < 64; ++j) rank += (skeys[j] < key) ? 1 : 0;
        idxout[n*64 + rank] = (int)(key & 0xffffffffu);
        d2out [n*64 + rank] = __uint_as_float((unsigned)(key >> 32));
    }
}

// ---------------------------------------------------------------------------
// per-(query,neighbor) geometry: 8 corner ids + trilinear*window weights
// ---------------------------------------------------------------------------
__global__ __launch_bounds__(256)
void geom_kernel(const float* __restrict__ qpos, const float* __restrict__ cpos,
                 const int* __restrict__ idxbuf, const float* __restrict__ d2buf,
                 unsigned char* __restrict__ corbuf, float* __restrict__ w8buf)
{
    int t = blockIdx.x*blockDim.x + threadIdx.x;
    if (t >= NF*64) return;
    int n = t >> 6;
    int m = idxbuf[t];
    float d2 = d2buf[t];
    float ox = cpos[m*3+0] - qpos[n*3+0];
    float oy = cpos[m*3+1] - qpos[n*3+1];
    float oz = cpos[m*3+2] - qpos[n*3+2];
    float ux = ox / 3.0f, uy = oy / 3.0f, uz = oz / 3.0f;   // radius = 3.0
    float r_sqr = ux*ux + uy*uy + uz*uz;
    float tt  = 1.0f - r_sqr;
    float win = tt*tt*tt;
    win = fminf(fmaxf(win, 0.0f), 1.0f);
    if (!(d2 <= 9.0f)) win = 0.0f;   // valid = selected d2 <= radius^2
    float b[3];
    ball_to_cube(ux, uy, uz, b);
    int c0[3]; float fr[3];
#pragma unroll
    for (int d = 0; d < 3; ++d) {
        float coords = (b[d]*0.5f + 0.5f) * 3.0f;
        coords = fminf(fmaxf(coords, 0.0f), 3.0f);
        float fl = floorf(coords);
        fl = fminf(fmaxf(fl, 0.0f), 2.0f);
        c0[d] = (int)fl;
        fr[d] = coords - fl;
    }
#pragma unroll
    for (int j = 0; j < 8; ++j) {
        int ix = (j>>2)&1, iy = (j>>1)&1, iz = j&1;
        int cid = ((c0[0]+ix)*4 + (c0[1]+iy))*4 + (c0[2]+iz);
        float wt = ((ix ? fr[0] : 1.0f-fr[0]) * (iy ? fr[1] : 1.0f-fr[1]))
                 *  (iz ? fr[2] : 1.0f-fr[2]);
        corbuf[(size_t)t*8 + j] = (unsigned char)cid;
        w8buf [(size_t)t*8 + j] = wt * win;
    }
}

// ---------------------------------------------------------------------------
// fused cconv: one block per query. LDS cell-accumulator [S][64][CP] built by
// scatter, then register-tiled contraction against kernel (NCELL,Cin,Cout).
// Cin processed in Csub chunks to stay under 64KB LDS.
// ---------------------------------------------------------------------------
template<int S>
__global__ __launch_bounds__(256)
void cconv_kernel(const float* __restrict__ feats, int fstride, int dorelu,
                  const int* __restrict__ idxbuf, const float* __restrict__ w8buf,
                  const unsigned char* __restrict__ corbuf,
                  const float* __restrict__ W, const float* __restrict__ bias,
                  float* __restrict__ outbuf, int ostride, int ooff,
                  int Cin, int Csub, int Cout)
{
    extern __shared__ float smem[];
    const int n   = blockIdx.x;
    const int tid = threadIdx.x;
    const int CP  = ((Csub & 3) == 0) ? (Csub + 4) : Csub;  // pad breaks bank conflicts
    float* cell = smem;                 // S*64*CP
    float* red  = smem + S*64*CP;       // 3072 floats (also hosts staging early)
    float* s_w8 = red;                            // 512 floats
    int*   s_idx = (int*)(red + 512);             // 64 ints
    unsigned char* s_cor = (unsigned char*)(red + 576);  // 512 bytes

    for (int i = tid; i < 512; i += 256) s_w8[i] = w8buf[(size_t)n*512 + i];
    if (tid < 64)  s_idx[tid] = idxbuf[n*64 + tid];
    if (tid < 128) ((uint32_t*)s_cor)[tid] = ((const uint32_t*)corbuf)[(size_t)n*128 + tid];
    __syncthreads();

    const bool vec = ((Cout & 3) == 0) && ((Csub & 3) == 0);
    const int OG = Cout >> 2;
    const int vchunks = 256 / OG;
    const int og  = tid % OG;
    const int vch = tid / OG;
    const int o4  = og * 4;
    const int CHS = (256 / Cout < 16) ? (256 / Cout) : 16;
    const int so  = tid % Cout;
    const int sch = tid / Cout;

    float acc[S][4];
#pragma unroll
    for (int s = 0; s < S; ++s) { acc[s][0]=0.f; acc[s][1]=0.f; acc[s][2]=0.f; acc[s][3]=0.f; }
    float accS[S];
#pragma unroll
    for (int s = 0; s < S; ++s) accS[s] = 0.f;

    for (int cb = 0; cb < Cin; cb += Csub) {
        for (int i = tid; i < S*64*CP; i += 256) cell[i] = 0.f;
        __syncthreads();

        // ---- scatter ----
        if ((Csub & 3) == 0) {
            // race-free: within a wave all concurrent lanes differ in (s,c4) or j,
            // and distinct j => distinct corner; waves have disjoint (s,c4) sets.
            int C4  = Csub >> 2;
            int nth = S * C4 * 4;
            if (tid < nth) {
                int j2  = tid & 3;
                int sc4 = tid >> 2;
                int s   = sc4 / C4;
                int c4  = (sc4 - s*C4) << 2;
                const float* fb = feats + s*Cin + cb + c4;
                float* cbse = cell + s*64*CP + c4;
                for (int k = 0; k < 64; ++k) {
                    int m = s_idx[k];
                    float4 v = *(const float4*)(fb + (size_t)m*fstride);
                    if (dorelu) {
                        v.x = fmaxf(v.x, 0.f); v.y = fmaxf(v.y, 0.f);
                        v.z = fmaxf(v.z, 0.f); v.w = fmaxf(v.w, 0.f);
                    }
#pragma unroll
                    for (int jj = 0; jj < 2; ++jj) {
                        int j = j2*2 + jj;
                        float wt = s_w8[k*8 + j];
                        int l = (int)s_cor[k*8 + j];
                        float4* cp = (float4*)(cbse + l*CP);
                        float4 cur = *cp;
                        cur.x = fmaf(wt, v.x, cur.x);
                        cur.y = fmaf(wt, v.y, cur.y);
                        cur.z = fmaf(wt, v.z, cur.z);
                        cur.w = fmaf(wt, v.w, cur.w);
                        *cp = cur;
                    }
                }
            }
        } else {
            int SCt = S * Csub;
            int total = 64*8*SCt;
            for (int t = tid; t < total; t += 256) {
                int k   = t / (8*SCt);
                int rem = t - k*8*SCt;
                int j   = rem / SCt;
                int sc  = rem - j*SCt;
                int s   = sc / Csub;
                int c   = sc - s*Csub;
                int m   = s_idx[k];
                float v = feats[(size_t)m*fstride + s*Cin + cb + c];
                if (dorelu) v = fmaxf(v, 0.f);
                atomicAdd(&cell[(s*64 + (int)s_cor[k*8+j])*CP + c], s_w8[k*8+j]*v);
            }
        }
        __syncthreads();

        // ---- partial contraction (acc persists across cb chunks) ----
        if (vec) {
            for (int l = vch; l < 64; l += vchunks) {
                const float* wrow = W + (size_t)(l*Cin + cb)*Cout + o4;
                for (int c2 = 0; c2 < Csub; c2 += 4) {
                    float4 cv[S];
#pragma unroll
                    for (int s = 0; s < S; ++s)
                        cv[s] = *(const float4*)(cell + (s*64 + l)*CP + c2);
#pragma unroll
                    for (int q = 0; q < 4; ++q) {
                        float4 w4 = *(const float4*)(wrow + (size_t)(c2 + q)*Cout);
#pragma unroll
                        for (int s = 0; s < S; ++s) {
                            float cvq = (q==0)?cv[s].x:((q==1)?cv[s].y:((q==2)?cv[s].z:cv[s].w));
                            acc[s][0] = fmaf(cvq, w4.x, acc[s][0]);
                            acc[s][1] = fmaf(cvq, w4.y, acc[s][1]);
                            acc[s][2] = fmaf(cvq, w4.z, acc[s][2]);
                            acc[s][3] = fmaf(cvq, w4.w, acc[s][3]);
                        }
                    }
                }
            }
        } else if (sch < CHS) {
            for (int l = 0; l < 64; ++l) {
                for (int c2 = sch; c2 < Csub; c2 += CHS) {
                    float wt = W[(size_t)(l*Cin + cb + c2)*Cout + so];
#pragma unroll
                    for (int s = 0; s < S; ++s)
                        accS[s] = fmaf(cell[(s*64 + l)*CP + c2], wt, accS[s]);
                }
            }
        }
        __syncthreads();
    }

    // ---- reduce partials, add bias, write ----
    if (vec) {
#pragma unroll
        for (int s = 0; s < S; ++s) {
            float* rp = red + (size_t)(vch*S + s)*Cout + o4;
            rp[0] = acc[s][0]; rp[1] = acc[s][1]; rp[2] = acc[s][2]; rp[3] = acc[s][3];
        }
    } else if (sch < CHS) {
#pragma unroll
        for (int s = 0; s < S; ++s)
            red[(size_t)(sch*S + s)*Cout + so] = accS[s];
    }
    __syncthreads();
    int chunksUsed = vec ? vchunks : CHS;
    for (int t = tid; t < S*Cout; t += 256) {
        int s = t / Cout, o = t - s*Cout;
        float sum = 0.f;
        for (int c2 = 0; c2 < chunksUsed; ++c2)
            sum += red[(size_t)(c2*S + s)*Cout + o];
        outbuf[((size_t)n*S + s)*ostride + ooff + o] = sum + bias[o];
    }
}

// ---------------------------------------------------------------------------
// dense shortcut: out[ns, ooff+o] (=|+=) relu?(in[ns,:]) @ Wd + bd (+ res)
// ---------------------------------------------------------------------------
__global__ __launch_bounds__(256)
void dense_kernel(const float* __restrict__ in, int CinT, int dorelu,
                  const float* __restrict__ Wd, const float* __restrict__ bd,
                  const float* __restrict__ res, int rstride,
                  float* __restrict__ outbuf, int ostride, int ooff,
                  int accumulate, int Cout, int Ntot)
{
    int t = blockIdx.x*blockDim.x + threadIdx.x;
    if (t >= Ntot) return;
    int o  = t % Cout;
    int ns = t / Cout;
    const float* row = in + (size_t)ns*CinT;
    float sum = bd[o];
    for (int c = 0; c < CinT; ++c) {
        float v = row[c];
        if (dorelu) v = fmaxf(v, 0.f);
        sum = fmaf(v, Wd[(size_t)c*Cout + o], sum);
    }
    if (res) sum += res[(size_t)ns*rstride + o];
    float* dst = outbuf + (size_t)ns*ostride + ooff + o;
    if (accumulate) *dst += sum; else *dst = sum;
}

__global__ __launch_bounds__(256)
void bcast_co_kernel(const float* __restrict__ co, float* __restrict__ out0, int total)
{
    int t = blockIdx.x*blockDim.x + threadIdx.x;
    if (t >= total) return;          // NF*3*32
    int o = t % 32; int ns = t / 32; int n = ns / 3;
    out0[(size_t)ns*96 + o] = co[n*32 + o];
}

__global__ __launch_bounds__(256)
void epilogue_kernel(const float* __restrict__ out4, const float* __restrict__ p1,
                     const float* __restrict__ p0, const float* __restrict__ v0enc,
                     float* __restrict__ dout)
{
    int t = blockIdx.x*blockDim.x + threadIdx.x;
    if (t >= NF*3) return;
    int n = t/3, j = t - 3*n;
    float corr = (0.25f * out4[n*9 + 0 + j]) * (1.0f/16.0f);
    float pc = p1[t] + corr;
    float vc = (pc - p0[t]) / 0.1f;
    dout[t] = pc;                                   // p_c
    dout[ 9000 + t] = vc;                           // v_c
    dout[18000 + n*6 + 0 + j] = 0.25f * out4[n*9 + 3 + j];  // m_matrix row 0
    dout[18000 + n*6 + 3 + j] = 0.25f * out4[n*9 + 6 + j];  // m_matrix row 1
    dout[36000 + t] = v0enc[t];                     // state_feats = v0_enc
}

// ---------------------------------------------------------------------------
extern "C" void kernel_launch(void* const* d_in, const int* in_sizes, int n_in,
                              void* d_out, int out_size, void* d_ws, size_t ws_size,
                              hipStream_t stream)
{
    const float* v0_enc   = (const float*)d_in[1];
    const float* p0       = (const float*)d_in[2];
    const float* v0       = (const float*)d_in[3];
    const float* a        = (const float*)d_in[4];
    const float* other    = (const float*)d_in[5];
    const float* box      = (const float*)d_in[6];
    const float* box_feat = (const float*)d_in[7];
    const float* box_mask = (const float*)d_in[9];
    const float* k0f = (const float*)d_in[10]; const float* b0f = (const float*)d_in[11];
    const float* k0o = (const float*)d_in[12]; const float* b0o = (const float*)d_in[13];
    const float* wdf = (const float*)d_in[14]; const float* bdf = (const float*)d_in[15];

    // setup_inputs() dict order interleaves kc/bc/wd/bd; fall back to signature
    // order if sizes say otherwise (in_sizes[18]: wd1=6144 vs kc2=262144).
    const float *kcv[4], *bcv[4], *wdv[4], *bdv[4];
    bool interleaved = (in_sizes[18] == 96*64);
    for (int i = 0; i < 4; ++i) {
        if (interleaved) {
            kcv[i] = (const float*)d_in[16 + 4*i + 0];
            bcv[i] = (const float*)d_in[16 + 4*i + 1];
            wdv[i] = (const float*)d_in[16 + 4*i + 2];
            bdv[i] = (const float*)d_in[16 + 4*i + 3];
        } else {
            kcv[i] = (const float*)d_in[16 + 2*i];
            bcv[i] = (const float*)d_in[17 + 2*i];
            wdv[i] = (const float*)d_in[24 + 2*i];
            bdv[i] = (const float*)d_in[25 + 2*i];
        }
    }

    // ---- workspace carve (≈21 MB) ----
    size_t off = 0;
    char* base = (char*)d_ws;
    auto carve = [&](size_t bytes) -> void* {
        void* p = base + off;
        off += (bytes + 255) & ~(size_t)255;
        return p;
    };
    float* p1    = (float*)carve(NF*3*sizeof(float));
    float* ff    = (float*)carve(NF*9*sizeof(float));
    int*   idx_f = (int*)  carve(NF*64*sizeof(int));
    float* d2_f  = (float*)carve(NF*64*sizeof(float));
    unsigned char* cor_f = (unsigned char*)carve((size_t)NF*64*8);
    float* w8_f  = (float*)carve((size_t)NF*64*8*sizeof(float));
    int*   idx_b = (int*)  carve(NF*64*sizeof(int));
    float* d2_b  = (float*)carve(NF*64*sizeof(float));
    unsigned char* cor_b = (unsigned char*)carve((size_t)NF*64*8);
    float* w8_b  = (float*)carve((size_t)NF*64*8*sizeof(float));
    float* out0  = (float*)carve((size_t)NF*3*96*sizeof(float));
    float* outA  = (float*)carve((size_t)NF*3*64*sizeof(float));
    float* outB  = (float*)carve((size_t)NF*3*64*sizeof(float));
    float* out4  = (float*)carve((size_t)NF*9*sizeof(float));
    float* co    = (float*)carve((size_t)NF*32*sizeof(float));
    (void)ws_size; (void)out_size; (void)n_in;

    // ---- 1. integrate ----
    integrate_kernel<<<(NF*3 + 255)/256, 256, 0, stream>>>(p0, v0, a, other, v0_enc, p1, ff);

    // ---- 2. neighbor search (exact top-64, JAX tie-break, sorted output) ----
    knn_kernel<12, true,  false><<<NF, 256, 0, stream>>>(p1, p1,  NF, nullptr,  idx_f, d2_f);
    knn_kernel< 6, false, true ><<<NF, 256, 0, stream>>>(p1, box, NB, box_mask, idx_b, d2_b);

    // ---- 3. geometry (shared by all convs on each neighbor list) ----
    geom_kernel<<<(NF*64 + 255)/256, 256, 0, stream>>>(p1, p1,  idx_f, d2_f, cor_f, w8_f);
    geom_kernel<<<(NF*64 + 255)/256, 256, 0, stream>>>(p1, box, idx_b, d2_b, cor_b, w8_b);

    auto conv3 = [&](const float* feats, int fstride, int dorelu,
                     const int* idx, const float* w8, const unsigned char* cor,
                     const float* W, const float* bias,
                     float* outb, int ostride, int ooff,
                     int Cin, int Csub, int Cout) {
        int CP = ((Csub & 3) == 0) ? Csub + 4 : Csub;
        size_t smem = (size_t)(3*64*CP + 3072)*sizeof(float);
        cconv_kernel<3><<<NF, 256, smem, stream>>>(feats, fstride, dorelu, idx, w8, cor,
                                                   W, bias, outb, ostride, ooff, Cin, Csub, Cout);
    };

    // ---- 4. layer 0: cf (fluid conv), co (box conv), df (dense) -> out0 ----
    conv3(ff, 9, 0, idx_f, w8_f, cor_f, k0f, b0f, out0, 96, 32, 3, 3, 32);
    {
        int CP = 1;
        size_t smem = (size_t)(1*64*CP + 3072)*sizeof(float);
        cconv_kernel<1><<<NF, 256, smem, stream>>>(box_feat, 1, 0, idx_b, w8_b, cor_b,
                                                   k0o, b0o, co, 32, 0, 1, 1, 32);
    }
    bcast_co_kernel<<<(NF*3*32 + 255)/256, 256, 0, stream>>>(co, out0, NF*3*32);
    dense_kernel<<<(NF*3*32 + 255)/256, 256, 0, stream>>>(ff, 3, 0, wdf, bdf,
                                                          nullptr, 0, out0, 96, 64, 0, 32, NF*3*32);

    // ---- 5. layer 1: 96 -> 64, no residual ----
    conv3(out0, 288, 1, idx_f, w8_f, cor_f, kcv[0], bcv[0], outA, 64, 0, 96, 48, 64);
    dense_kernel<<<(NF*3*64 + 255)/256, 256, 0, stream>>>(out0, 96, 1, wdv[0], bdv[0],
                                                          nullptr, 0, outA, 64, 0, 1, 64, NF*3*64);

    // ---- 6. layer 2: 64 -> 64, residual ----
    conv3(outA, 192, 1, idx_f, w8_f, cor_f, kcv[1], bcv[1], outB, 64, 0, 64, 64, 64);
    dense_kernel<<<(NF*3*64 + 255)/256, 256, 0, stream>>>(outA, 64, 1, wdv[1], bdv[1],
                                                          outA, 64, outB, 64, 0, 1, 64, NF*3*64);

    // ---- 7. layer 3: 64 -> 64, residual ----
    conv3(outB, 192, 1, idx_f, w8_f, cor_f, kcv[2], bcv[2], outA, 64, 0, 64, 64, 64);
    dense_kernel<<<(NF*3*64 + 255)/256, 256, 0, stream>>>(outB, 64, 1, wdv[2], bdv[2],
                                                          outB, 64, outA, 64, 0, 1, 64, NF*3*64);

    // ---- 8. layer 4: 64 -> 3, no residual ----
    conv3(outA, 192, 1, idx_f, w8_f, cor_f, kcv[3], bcv[3], out4, 3, 0, 64, 64, 3);
    dense_kernel<<<(NF*3*3 + 255)/256, 256, 0, stream>>>(outA, 64, 1, wdv[3], bdv[3],
                                                         nullptr, 0, out4, 3, 0, 1, 3, NF*3*3);

    // ---- 9. epilogue -> d_out ----
    epilogue_kernel<<<(NF*3 + 255)/256, 256, 0, stream>>>(out4, p1, p0, v0_enc, (float*)d_out);
}

// Round 5
// 1593.667 us; speedup vs baseline: 1.0962x; 1.0962x over previous
//
#include <hip/hip_runtime.h>
#include <stdint.h>

#define NF 3000
#define NB 1500
#define KSMAX 8

// ---------------------------------------------------------------------------
// math helpers
// ---------------------------------------------------------------------------
__device__ __forceinline__ float signf(float v) {
    return (v > 0.f) ? 1.f : ((v < 0.f) ? -1.f : 0.f);
}

__device__ void ball_to_cube(float x, float y, float z, float b[3])
{
    const float EPS = 1e-8f;
    const float FOUR_OVER_PI = 1.2732395447351628f;
    float sq    = x*x + y*y + z*z;
    float norm  = sqrtf(fmaxf(sq, EPS));
    float xy_sq = x*x + y*y;
    bool  polar = (1.25f*z*z > xy_sq);
    float s_p = sqrtf(3.0f*norm / (norm + fabsf(z) + EPS));
    float s_e = norm / sqrtf(fmaxf(xy_sq, EPS));
    float cx = polar ? x*s_p : x*s_e;
    float cy = polar ? y*s_p : y*s_e;
    float cz = polar ? signf(z)*norm : 1.5f*z;
    float nxy = sqrtf(fmaxf(cx*cx + cy*cy, EPS));
    bool  xdom = fabsf(cy) <= fabsf(cx);
    float sx = (fabsf(cx) > EPS) ? cx : 1.0f;
    float sy = (fabsf(cy) > EPS) ? cy : 1.0f;
    float bx1 = signf(cx)*nxy;
    float by1 = bx1*FOUR_OVER_PI*atanf(cy/sx);
    float by2 = signf(cy)*nxy;
    float bx2 = by2*FOUR_OVER_PI*atanf(cx/sy);
    float bx = xdom ? bx1 : bx2;
    float by = xdom ? by1 : by2;
    if (cx*cx + cy*cy < EPS) { bx = 0.f; by = 0.f; }
    if (sq < EPS)            { bx = 0.f; by = 0.f; cz = 0.f; }
    b[0] = bx; b[1] = by; b[2] = cz;
}

// ---------------------------------------------------------------------------
// integrate
// ---------------------------------------------------------------------------
__global__ __launch_bounds__(256)
void integrate_kernel(const float* __restrict__ p0, const float* __restrict__ v0,
                      const float* __restrict__ a,  const float* __restrict__ other,
                      const float* __restrict__ v0enc,
                      float* __restrict__ p1, float* __restrict__ ff)
{
    int t = blockIdx.x*blockDim.x + threadIdx.x;
    if (t >= NF*3) return;
    float vv = v0[t];
    float v1 = vv + 0.1f*a[t];
    float u  = vv + v1;
    float u2 = 0.1f*u;
    float u3 = u2*0.5f;
    p1[t] = p0[t] + u3;
    int n = t/3, j = t - 3*n;
    ff[n*9 + 0 + j] = v1;
    ff[n*9 + 3 + j] = other[t];
    ff[n*9 + 6 + j] = v0enc[t];
}

// ---------------------------------------------------------------------------
// exact top-64 (== jax.lax.top_k order): radix select + rank sort.
// shfl-based histogram scan (3-4 barriers/pass instead of 16).
// ---------------------------------------------------------------------------
template<int LPT, bool SELFX, bool MASK>
__global__ __launch_bounds__(256)
void knn_kernel(const float* __restrict__ qpos, const float* __restrict__ cpos, int M,
                const float* __restrict__ mask, int* __restrict__ idxout)
{
    __shared__ unsigned hist[256];
    __shared__ unsigned wtot[4];
    __shared__ unsigned long long s_prefix;
    __shared__ int s_rem;
    __shared__ int s_cnt;
    __shared__ uint64_t skeys[64];

    int n = blockIdx.x;
    int tid = threadIdx.x;
    float qx = qpos[n*3+0], qy = qpos[n*3+1], qz = qpos[n*3+2];

    uint64_t keys[LPT];
#pragma unroll
    for (int i = 0; i < LPT; ++i) {
        int c = i*256 + tid;
        uint64_t key = ~0ull;
        if (c < M) {
            float dx = __fadd_rn(qx, -cpos[c*3+0]);
            float dy = __fadd_rn(qy, -cpos[c*3+1]);
            float dz = __fadd_rn(qz, -cpos[c*3+2]);
            float d2 = __fadd_rn(__fadd_rn(__fmul_rn(dx,dx), __fmul_rn(dy,dy)),
                                 __fmul_rn(dz,dz));
            if (SELFX && c == n) d2 = 1e30f;
            if (MASK && !(mask[c] > 0.f)) d2 = 1e30f;
            key = ((uint64_t)__float_as_uint(d2) << 32) | (unsigned)c;
        }
        keys[i] = key;
    }

    uint64_t prefix = 0;
    int rem = 64;
    for (int pass = 0; pass < 8; ++pass) {
        int shift = 56 - 8*pass;
        hist[tid] = 0;
        __syncthreads();
#pragma unroll
        for (int i = 0; i < LPT; ++i) {
            uint64_t k = keys[i];
            bool act = (((k >> shift) >> 8) == prefix);   // pass0: ==0
            if (act) atomicAdd(&hist[(unsigned)((k >> shift) & 0xff)], 1u);
        }
        __syncthreads();
        unsigned own = hist[tid];
        // wave-level inclusive scan (64 lanes, no barriers)
        unsigned v = own;
#pragma unroll
        for (int o2 = 1; o2 < 64; o2 <<= 1) {
            unsigned u = (unsigned)__shfl_up((int)v, o2, 64);
            if ((tid & 63) >= o2) v += u;
        }
        if ((tid & 63) == 63) wtot[tid >> 6] = v;
        __syncthreads();
        unsigned bsum = 0;
#pragma unroll
        for (int w = 0; w < 4; ++w) bsum += (w < (tid >> 6)) ? wtot[w] : 0u;
        unsigned inc = v + bsum;
        unsigned exc = inc - own;
        if (exc < (unsigned)rem && inc >= (unsigned)rem) {  // exactly one tid
            s_prefix = (prefix << 8) | (unsigned)tid;
            s_rem = rem - (int)exc;
        }
        __syncthreads();
        prefix = s_prefix;
        rem = s_rem;
        __syncthreads();
    }
    uint64_t kth = prefix;
    if (tid == 0) s_cnt = 0;
    __syncthreads();
#pragma unroll
    for (int i = 0; i < LPT; ++i) {
        uint64_t k = keys[i];
        if (k <= kth) {
            int p = atomicAdd(&s_cnt, 1);
            skeys[p] = k;
        }
    }
    __syncthreads();
    if (tid < 64) {
        uint64_t key = skeys[tid];
        int rank = 0;
        for (int j = 0; j < 64; ++j) rank += (skeys[j] < key) ? 1 : 0;
        idxout[n*64 + rank] = (int)(key & 0xffffffffu);
    }
}

// ---------------------------------------------------------------------------
// geometry: recomputes d2 (same rn ops as knn; sign of offset irrelevant for
// squares). valid cutoff sits at win==0 so boundary drift is harmless.
// ---------------------------------------------------------------------------
__global__ __launch_bounds__(256)
void geom_kernel(const float* __restrict__ qpos, const float* __restrict__ cpos,
                 const int* __restrict__ idxbuf, int selfex,
                 unsigned char* __restrict__ corbuf, float* __restrict__ w8buf)
{
    int t = blockIdx.x*blockDim.x + threadIdx.x;
    if (t >= NF*64) return;
    int n = t >> 6;
    int m = idxbuf[t];
    float ox = __fadd_rn(cpos[m*3+0], -qpos[n*3+0]);
    float oy = __fadd_rn(cpos[m*3+1], -qpos[n*3+1]);
    float oz = __fadd_rn(cpos[m*3+2], -qpos[n*3+2]);
    float d2 = __fadd_rn(__fadd_rn(__fmul_rn(ox,ox), __fmul_rn(oy,oy)),
                         __fmul_rn(oz,oz));
    bool valid = (d2 <= 9.0f) && !(selfex && m == n);
    float ux = ox / 3.0f, uy = oy / 3.0f, uz = oz / 3.0f;
    float r_sqr = ux*ux + uy*uy + uz*uz;
    float tt  = 1.0f - r_sqr;
    float win = tt*tt*tt;
    win = fminf(fmaxf(win, 0.0f), 1.0f);
    if (!valid) win = 0.0f;
    float b[3];
    ball_to_cube(ux, uy, uz, b);
    int c0[3]; float fr[3];
#pragma unroll
    for (int d = 0; d < 3; ++d) {
        float coords = (b[d]*0.5f + 0.5f) * 3.0f;
        coords = fminf(fmaxf(coords, 0.0f), 3.0f);
        float fl = floorf(coords);
        fl = fminf(fmaxf(fl, 0.0f), 2.0f);
        c0[d] = (int)fl;
        fr[d] = coords - fl;
    }
#pragma unroll
    for (int j = 0; j < 8; ++j) {
        int ix = (j>>2)&1, iy = (j>>1)&1, iz = j&1;
        int cid = ((c0[0]+ix)*4 + (c0[1]+iy))*4 + (c0[2]+iz);
        float wt = ((ix ? fr[0] : 1.0f-fr[0]) * (iy ? fr[1] : 1.0f-fr[1]))
                 *  (iz ? fr[2] : 1.0f-fr[2]);
        corbuf[(size_t)t*8 + j] = (unsigned char)cid;
        w8buf [(size_t)t*8 + j] = wt * win;
    }
}

// ---------------------------------------------------------------------------
// scatter: A[(n,s)][l*C+c] = sum_{k,j} w8 * relu?(h[m_k, s, c])
// block per query; thread per channel f=s*C+c (race/conflict-free)
// ---------------------------------------------------------------------------
__global__ __launch_bounds__(256)
void scatter_kernel(const float* __restrict__ h, int C3, int C, int relu_,
                    const int* __restrict__ idxbuf, const float* __restrict__ w8buf,
                    const unsigned char* __restrict__ corbuf,
                    int Kconv, int n0, float* __restrict__ A)
{
    extern __shared__ float sm[];
    float* s_w8 = sm;                                    // 512
    int*   s_idx = (int*)(sm + 512);                     // 64
    unsigned char* s_cor = (unsigned char*)(sm + 576);   // 512 B
    float* cell = sm + 704;                              // 64*FC

    int nloc = blockIdx.x;
    int n = n0 + nloc;
    int tid = threadIdx.x;
    for (int i = tid; i < 512; i += 256) s_w8[i] = w8buf[(size_t)n*512 + i];
    if (tid < 64)  s_idx[tid] = idxbuf[n*64 + tid];
    if (tid < 128) ((uint32_t*)s_cor)[tid] = ((const uint32_t*)corbuf)[(size_t)n*128 + tid];
    __syncthreads();

    int FC = (C3 <= 256) ? C3 : ((C3 + 1) >> 1);
    int nch = (C3 + FC - 1) / FC;
    for (int ch = 0; ch < nch; ++ch) {
        int fbase = ch * FC;
        for (int i = tid; i < 64*FC; i += 256) cell[i] = 0.f;
        __syncthreads();
        bool act = (tid < FC) && (fbase + tid < C3);
        int fg = fbase + tid;
        if (act) {
            float* cl = cell + tid;
#pragma unroll 2
            for (int k = 0; k < 64; ++k) {
                int m = s_idx[k];
                float v = h[(size_t)m*C3 + fg];
                if (relu_) v = fmaxf(v, 0.f);
#pragma unroll
                for (int j = 0; j < 8; ++j) {
                    int l = (int)s_cor[k*8 + j];
                    cl[l*FC] = fmaf(s_w8[k*8 + j], v, cl[l*FC]);
                }
            }
        }
        __syncthreads();
        if (act) {
            int s = fg / C, c = fg - s*C;
            float* dst = A + ((size_t)(nloc*3 + s))*Kconv + c;
            const float* src = cell + tid;
            for (int l = 0; l < 64; ++l)
                dst[l*C] = src[(size_t)l*FC];
        }
        __syncthreads();
    }
}

// ---------------------------------------------------------------------------
// box scatter (S=1,C=1)
// ---------------------------------------------------------------------------
__global__ __launch_bounds__(64)
void boxscatter_kernel(const float* __restrict__ bf, const int* __restrict__ idxbuf,
                       const float* __restrict__ w8buf, const unsigned char* __restrict__ corbuf,
                       float* __restrict__ Ab)
{
    __shared__ float wf[512];
    __shared__ int   sc[512];
    int n = blockIdx.x, tid = threadIdx.x;
    for (int i = tid; i < 512; i += 64) {
        int k = i >> 3;
        int m = idxbuf[n*64 + k];
        wf[i] = w8buf[(size_t)n*512 + i] * bf[m];
        sc[i] = (int)corbuf[(size_t)n*512 + i];
    }
    __syncthreads();
    float acc = 0.f;
    for (int i = 0; i < 512; ++i) acc += (sc[i] == tid) ? wf[i] : 0.f;
    Ab[n*64 + tid] = acc;
}

// ---------------------------------------------------------------------------
// tiled GEMM, split-K, fused dense-tail K-columns.
// KS>1: write partials P[KS][M][64]. KS==1: write output directly with
// bias b1(+b2) (+res).
// ---------------------------------------------------------------------------
#define GBM 64
#define GBN 64
#define GBK 32
__global__ __launch_bounds__(256)
void gemm_kernel(const float* __restrict__ A, int Kconv,
                 const float* __restrict__ htail, int C, int hrow0, int relu_,
                 const float* __restrict__ Wc, const float* __restrict__ Wd,
                 int M, int N, int Ktot, int KS, float* __restrict__ P,
                 float* __restrict__ outp, int ostride, int ooff,
                 const float* __restrict__ b1, const float* __restrict__ b2,
                 const float* __restrict__ res, int rstride)
{
    __shared__ float At[GBK][GBM+4];
    __shared__ float Bs[GBK][GBN+4];
    int mt = blockIdx.x * GBM;
    int ks = blockIdx.y;
    int nbk = (Ktot + GBK*KS - 1) / (GBK*KS);
    int k0 = ks * nbk * GBK;
    int k1 = min(Ktot, k0 + nbk*GBK);
    int tid = threadIdx.x;
    int tn = tid & 15, tm = tid >> 4;

    float acc[4][4];
#pragma unroll
    for (int i = 0; i < 4; ++i)
#pragma unroll
        for (int j = 0; j < 4; ++j) acc[i][j] = 0.f;

    for (int kb = k0; kb < k1; kb += GBK) {
#pragma unroll
        for (int half = 0; half < 2; ++half) {
            int t = tid + half*256;
            int row = t >> 3, kq = (t & 7) << 2;
            int grow = mt + row, gk = kb + kq;
            float4 v = make_float4(0.f,0.f,0.f,0.f);
            if (grow < M) {
                if (gk < Kconv) {
                    v = *(const float4*)(A + (size_t)grow*Kconv + gk);
                } else {
                    v = *(const float4*)(htail + (size_t)(hrow0+grow)*C + (gk - Kconv));
                    if (relu_) {
                        v.x = fmaxf(v.x,0.f); v.y = fmaxf(v.y,0.f);
                        v.z = fmaxf(v.z,0.f); v.w = fmaxf(v.w,0.f);
                    }
                }
            }
            At[kq+0][row] = v.x; At[kq+1][row] = v.y;
            At[kq+2][row] = v.z; At[kq+3][row] = v.w;
        }
#pragma unroll
        for (int half = 0; half < 2; ++half) {
            int t = tid + half*256;
            int krow = t >> 4, nq = (t & 15) << 2;
            int gk = kb + krow;
            float4 v = make_float4(0.f,0.f,0.f,0.f);
            if (nq < N) {
                if (gk < Kconv) v = *(const float4*)(Wc + (size_t)gk*N + nq);
                else            v = *(const float4*)(Wd + (size_t)(gk - Kconv)*N + nq);
            }
            *(float4*)&Bs[krow][nq] = v;
        }
        __syncthreads();
#pragma unroll
        for (int kk = 0; kk < GBK; ++kk) {
            float4 a4 = *(const float4*)&At[kk][tm<<2];
            float4 b4 = *(const float4*)&Bs[kk][tn<<2];
            float av[4] = {a4.x, a4.y, a4.z, a4.w};
            float bv[4] = {b4.x, b4.y, b4.z, b4.w};
#pragma unroll
            for (int i = 0; i < 4; ++i)
#pragma unroll
                for (int j = 0; j < 4; ++j)
                    acc[i][j] = fmaf(av[i], bv[j], acc[i][j]);
        }
        __syncthreads();
    }
    if (KS > 1) {
#pragma unroll
        for (int i = 0; i < 4; ++i) {
            int grow = mt + (tm<<2) + i;
            if (grow < M) {
                float4 st = make_float4(acc[i][0], acc[i][1], acc[i][2], acc[i][3]);
                *(float4*)(P + ((size_t)ks*M + grow)*64 + (tn<<2)) = st;
            }
        }
    } else {
        int o = tn << 2;
#pragma unroll
        for (int i = 0; i < 4; ++i) {
            int grow = mt + (tm<<2) + i;
            if (grow < M && o < N) {
                float4 st;
                st.x = acc[i][0] + b1[o+0] + (b2 ? b2[o+0] : 0.f);
                st.y = acc[i][1] + b1[o+1] + (b2 ? b2[o+1] : 0.f);
                st.z = acc[i][2] + b1[o+2] + (b2 ? b2[o+2] : 0.f);
                st.w = acc[i][3] + b1[o+3] + (b2 ? b2[o+3] : 0.f);
                if (res) {
                    st.x += res[(size_t)grow*rstride + o+0];
                    st.y += res[(size_t)grow*rstride + o+1];
                    st.z += res[(size_t)grow*rstride + o+2];
                    st.w += res[(size_t)grow*rstride + o+3];
                }
                *(float4*)(outp + (size_t)grow*ostride + ooff + o) = st;
            }
        }
    }
}

// ---------------------------------------------------------------------------
// split-K reduce + bias b1(+b2) (+res)
// ---------------------------------------------------------------------------
__global__ __launch_bounds__(256)
void reduce_kernel(const float* __restrict__ P, int KS, int M, int N,
                   const float* __restrict__ b1, const float* __restrict__ b2,
                   const float* __restrict__ res, int rstride,
                   float* __restrict__ out, int ostride, int ooff)
{
    int t = blockIdx.x*256 + threadIdx.x;
    if (t >= M*N) return;
    int row = t / N, o = t - row*N;
    float s = b1[o] + (b2 ? b2[o] : 0.f);
    for (int k = 0; k < KS; ++k) s += P[((size_t)k*M + row)*64 + o];
    if (res) s += res[(size_t)row*rstride + o];
    out[(size_t)row*ostride + ooff + o] = s;
}

// ---------------------------------------------------------------------------
// N=3 final layer: wave per row
// ---------------------------------------------------------------------------
__global__ __launch_bounds__(256)
void rowdot3_kernel(const float* __restrict__ A, int Kconv,
                    const float* __restrict__ h, int C, int hrow0,
                    const float* __restrict__ Wc, const float* __restrict__ Wd,
                    const float* __restrict__ bc, const float* __restrict__ bd,
                    int M, float* __restrict__ out)
{
    int row = blockIdx.x*4 + (threadIdx.x >> 6);
    int lane = threadIdx.x & 63;
    if (row >= M) return;
    const float* ar = A + (size_t)row*Kconv;
    const float* hr = h + (size_t)(hrow0+row)*C;
    float a0 = 0.f, a1 = 0.f, a2 = 0.f;
    int Ktot = Kconv + C;
    for (int k = lane; k < Ktot; k += 64) {
        float av; const float* w;
        if (k < Kconv) { av = ar[k];                   w = Wc + (size_t)k*3; }
        else           { av = fmaxf(hr[k-Kconv], 0.f); w = Wd + (size_t)(k-Kconv)*3; }
        a0 = fmaf(av, w[0], a0);
        a1 = fmaf(av, w[1], a1);
        a2 = fmaf(av, w[2], a2);
    }
    for (int off = 32; off > 0; off >>= 1) {
        a0 += __shfl_xor(a0, off);
        a1 += __shfl_xor(a1, off);
        a2 += __shfl_xor(a2, off);
    }
    if (lane == 0) {
        size_t o = (size_t)(hrow0+row)*3;
        out[o+0] = a0 + bc[0] + bd[0];
        out[o+1] = a1 + bc[1] + bd[1];
        out[o+2] = a2 + bc[2] + bd[2];
    }
}

// ---------------------------------------------------------------------------
__global__ __launch_bounds__(256)
void dense_kernel(const float* __restrict__ in, int CinT, int dorelu,
                  const float* __restrict__ Wd, const float* __restrict__ bd,
                  float* __restrict__ outbuf, int ostride, int ooff,
                  int Cout, int Ntot)
{
    int t = blockIdx.x*blockDim.x + threadIdx.x;
    if (t >= Ntot) return;
    int o  = t % Cout;
    int ns = t / Cout;
    const float* row = in + (size_t)ns*CinT;
    float sum = bd[o];
    for (int c = 0; c < CinT; ++c) {
        float v = row[c];
        if (dorelu) v = fmaxf(v, 0.f);
        sum = fmaf(v, Wd[(size_t)c*Cout + o], sum);
    }
    outbuf[(size_t)ns*ostride + ooff + o] = sum;
}

__global__ __launch_bounds__(256)
void bcast_co_kernel(const float* __restrict__ co, float* __restrict__ out0, int total)
{
    int t = blockIdx.x*blockDim.x + threadIdx.x;
    if (t >= total) return;
    int o = t % 32; int ns = t / 32; int n = ns / 3;
    out0[(size_t)ns*96 + o] = co[n*32 + o];
}

__global__ __launch_bounds__(256)
void epilogue_kernel(const float* __restrict__ out4, const float* __restrict__ p1,
                     const float* __restrict__ p0, const float* __restrict__ v0enc,
                     float* __restrict__ dout)
{
    int t = blockIdx.x*blockDim.x + threadIdx.x;
    if (t >= NF*3) return;
    int n = t/3, j = t - 3*n;
    float corr = (0.25f * out4[n*9 + 0 + j]) * (1.0f/16.0f);
    float pc = p1[t] + corr;
    float vc = (pc - p0[t]) / 0.1f;
    dout[t] = pc;
    dout[ 9000 + t] = vc;
    dout[18000 + n*6 + 0 + j] = 0.25f * out4[n*9 + 3 + j];
    dout[18000 + n*6 + 3 + j] = 0.25f * out4[n*9 + 6 + j];
    dout[36000 + t] = v0enc[t];
}

// ---------------------------------------------------------------------------
extern "C" void kernel_launch(void* const* d_in, const int* in_sizes, int n_in,
                              void* d_out, int out_size, void* d_ws, size_t ws_size,
                              hipStream_t stream)
{
    const float* v0_enc   = (const float*)d_in[1];
    const float* p0       = (const float*)d_in[2];
    const float* v0       = (const float*)d_in[3];
    const float* a        = (const float*)d_in[4];
    const float* other    = (const float*)d_in[5];
    const float* box      = (const float*)d_in[6];
    const float* box_feat = (const float*)d_in[7];
    const float* box_mask = (const float*)d_in[9];
    const float* k0f = (const float*)d_in[10]; const float* b0f = (const float*)d_in[11];
    const float* k0o = (const float*)d_in[12]; const float* b0o = (const float*)d_in[13];
    const float* wdf = (const float*)d_in[14]; const float* bdf = (const float*)d_in[15];

    const float *kcv[4], *bcv[4], *wdv[4], *bdv[4];
    bool interleaved = (in_sizes[18] == 96*64);
    for (int i = 0; i < 4; ++i) {
        if (interleaved) {
            kcv[i] = (const float*)d_in[16 + 4*i + 0];
            bcv[i] = (const float*)d_in[16 + 4*i + 1];
            wdv[i] = (const float*)d_in[16 + 4*i + 2];
            bdv[i] = (const float*)d_in[16 + 4*i + 3];
        } else {
            kcv[i] = (const float*)d_in[16 + 2*i];
            bcv[i] = (const float*)d_in[17 + 2*i];
            wdv[i] = (const float*)d_in[24 + 2*i];
            bdv[i] = (const float*)d_in[25 + 2*i];
        }
    }

    // ---- carve: PERSIST block (17.0 MB), then FREEABLE block (9.3 MB) ----
    // total fixed 26.4 MB <= 27.1 MB proven ws floor (round-3 PASS).
    size_t off = 0;
    char* base = (char*)d_ws;
    auto carve = [&](size_t bytes) -> void* {
        void* p = base + off;
        off += (bytes + 255) & ~(size_t)255;
        return p;
    };
    // persist
    float* p1    = (float*)carve(NF*3*sizeof(float));
    int*   idx_f = (int*)  carve(NF*64*sizeof(int));
    unsigned char* cor_f = (unsigned char*)carve((size_t)NF*512);
    float* w8_f  = (float*)carve((size_t)NF*512*sizeof(float));
    float* out0  = (float*)carve((size_t)NF*3*96*sizeof(float));
    float* outA  = (float*)carve((size_t)NF*3*64*sizeof(float));
    float* outB  = (float*)carve((size_t)NF*3*64*sizeof(float));
    float* out4  = (float*)carve((size_t)NF*9*sizeof(float));
    float* co    = (float*)carve((size_t)NF*32*sizeof(float));
    // freeable after layer 0
    size_t free_off = off;
    float* ff    = (float*)carve(NF*9*sizeof(float));
    int*   idx_b = (int*)  carve(NF*64*sizeof(int));
    unsigned char* cor_b = (unsigned char*)carve((size_t)NF*512);
    float* w8_b  = (float*)carve((size_t)NF*512*sizeof(float));
    float* A_b   = (float*)carve((size_t)NF*64*sizeof(float));
    size_t fixed_end = off;
    (void)out_size; (void)n_in;

    // layer-0 variable region: beyond fixed (>= 0.7 MB guaranteed)
    char*  v0base = base + fixed_end;
    size_t V0 = (ws_size > fixed_end) ? ws_size - fixed_end : 0;
    // layers 1-4 variable region: overlays freeable (>= 10 MB guaranteed)
    char*  v1base = base + free_off;
    size_t V1 = (ws_size > free_off) ? ws_size - free_off : 0;

    auto pickKS = [&](int Mch, int Ktot) -> int {
        int nb = (Mch + GBM - 1) / GBM;
        int ks = (1024 + nb - 1) / nb;
        if (ks > KSMAX) ks = KSMAX;
        int kt = Ktot / GBK; if (ks > kt) ks = kt;
        if (ks < 1) ks = 1;
        return ks;
    };

    // ---- 1. integrate ----
    integrate_kernel<<<(NF*3 + 255)/256, 256, 0, stream>>>(p0, v0, a, other, v0_enc, p1, ff);

    // ---- 2. knn ----
    knn_kernel<12, true,  false><<<NF, 256, 0, stream>>>(p1, p1,  NF, nullptr,  idx_f);
    knn_kernel< 6, false, true ><<<NF, 256, 0, stream>>>(p1, box, NB, box_mask, idx_b);

    // ---- 3. geometry ----
    geom_kernel<<<(NF*64 + 255)/256, 256, 0, stream>>>(p1, p1,  idx_f, 1, cor_f, w8_f);
    geom_kernel<<<(NF*64 + 255)/256, 256, 0, stream>>>(p1, box, idx_b, 0, cor_b, w8_b);

    // ---- 4. layer 0 ----
    // cf: fluid conv C=3 -> out0 cols 32..63 (KS=1 direct, chunked in V0)
    {
        int C = 3, C3 = 9, Kconv = 192;
        size_t smem = (704 + (size_t)64*C3) * sizeof(float);
        size_t bpq = (size_t)3*Kconv*4;
        int qpc = (int)(V0 / bpq);
        if (qpc < 1) qpc = 1;
        if (qpc > NF) qpc = NF;
        for (int n0 = 0; n0 < NF; n0 += qpc) {
            int nq = (NF - n0 < qpc) ? (NF - n0) : qpc;
            int Mch = nq*3;
            float* Achunk = (float*)v0base;
            scatter_kernel<<<nq, 256, smem, stream>>>(ff, C3, C, 0, idx_f, w8_f, cor_f,
                                                      Kconv, n0, Achunk);
            dim3 g((Mch + GBM - 1)/GBM, 1);
            gemm_kernel<<<g, 256, 0, stream>>>(Achunk, Kconv, nullptr, 0, 0, 0,
                                               k0f, nullptr, Mch, 32, Kconv, 1, nullptr,
                                               out0 + (size_t)n0*3*96, 96, 32,
                                               b0f, nullptr, nullptr, 0);
        }
    }
    // co: box conv (A_b fixed, KS=1 direct -> co) + broadcast
    {
        boxscatter_kernel<<<NF, 64, 0, stream>>>(box_feat, idx_b, w8_b, cor_b, A_b);
        dim3 g((NF + GBM - 1)/GBM, 1);
        gemm_kernel<<<g, 256, 0, stream>>>(A_b, 64, nullptr, 0, 0, 0,
                                           k0o, nullptr, NF, 32, 64, 1, nullptr,
                                           co, 32, 0, b0o, nullptr, nullptr, 0);
        bcast_co_kernel<<<(NF*3*32 + 255)/256, 256, 0, stream>>>(co, out0, NF*3*32);
    }
    // df: dense K=3 -> out0 cols 64..95
    dense_kernel<<<(NF*3*32 + 255)/256, 256, 0, stream>>>(ff, 3, 0, wdf, bdf,
                                                          out0, 96, 64, 32, NF*3*32);

    // ---- layers 1..4: scatter -> gemm(+tail) -> reduce, chunked in V1 ----
    // NOTE: freeable block (ff/idx_b/cor_b/w8_b/A_b) is dead from here on.
    auto convLayer = [&](const float* h, int C, const float* Wc, const float* bc,
                         const float* Wd, const float* bd,
                         const float* res, int rstride,
                         float* outp, int ostride, int Nout) {
        int Kconv = 64*C, C3 = 3*C;
        int Ktot = Kconv + C;
        int FC = (C3 <= 256) ? C3 : ((C3 + 1) >> 1);
        size_t smem = (704 + (size_t)64*FC) * sizeof(float);
        size_t bpq = (size_t)3*Kconv*4 + (size_t)3*KSMAX*64*4;
        int qpc = (int)(V1 / bpq);
        if (qpc < 1) qpc = 1;
        if (qpc > NF) qpc = NF;
        size_t Aoff = ((size_t)qpc*3*Kconv*4 + 255) & ~(size_t)255;
        for (int n0 = 0; n0 < NF; n0 += qpc) {
            int nq = (NF - n0 < qpc) ? (NF - n0) : qpc;
            int Mch = nq*3;
            float* Achunk = (float*)v1base;
            float* Play   = (float*)(v1base + Aoff);
            scatter_kernel<<<nq, 256, smem, stream>>>(h, C3, C, 1, idx_f, w8_f, cor_f,
                                                      Kconv, n0, Achunk);
            if (Nout == 3) {
                rowdot3_kernel<<<(Mch + 3)/4, 256, 0, stream>>>(Achunk, Kconv, h, C, n0*3,
                                                                Wc, Wd, bc, bd, Mch, out4);
            } else {
                int KS = pickKS(Mch, Ktot);
                dim3 g((Mch + GBM - 1)/GBM, KS);
                if (KS > 1) {
                    gemm_kernel<<<g, 256, 0, stream>>>(Achunk, Kconv, h, C, n0*3, 1,
                                                       Wc, Wd, Mch, Nout, Ktot, KS, Play,
                                                       nullptr, 0, 0, nullptr, nullptr,
                                                       nullptr, 0);
                    reduce_kernel<<<((size_t)Mch*Nout + 255)/256, 256, 0, stream>>>(
                        Play, KS, Mch, Nout, bc, bd,
                        res ? res + (size_t)n0*3*rstride : nullptr, rstride,
                        outp + (size_t)n0*3*ostride, ostride, 0);
                } else {
                    gemm_kernel<<<g, 256, 0, stream>>>(Achunk, Kconv, h, C, n0*3, 1,
                                                       Wc, Wd, Mch, Nout, Ktot, 1, nullptr,
                                                       outp + (size_t)n0*3*ostride, ostride, 0,
                                                       bc, bd,
                                                       res ? res + (size_t)n0*3*rstride : nullptr,
                                                       rstride);
                }
            }
        }
    };

    convLayer(out0, 96, kcv[0], bcv[0], wdv[0], bdv[0], nullptr, 0,  outA, 64, 64);
    convLayer(outA, 64, kcv[1], bcv[1], wdv[1], bdv[1], outA,   64, outB, 64, 64);
    convLayer(outB, 64, kcv[2], bcv[2], wdv[2], bdv[2], outB,   64, outA, 64, 64);
    convLayer(outA, 64, kcv[3], bcv[3], wdv[3], bdv[3], nullptr, 0,  out4, 3,  3);

    // ---- 9. epilogue ----
    epilogue_kernel<<<(NF*3 + 255)/256, 256, 0, stream>>>(out4, p1, p0, v0_enc, (float*)d_out);
}